// Round 1
// baseline (68810.034 us; speedup 1.0000x reference)
//
#include <hip/hip_runtime.h>
#include <cmath>

#define L_ 512
#define B_ 128
#define D_ 1024
#define H_ 1024

// ---------------------------------------------------------------------------
// Kernel A: xi[m][h] = dot(x[m,:], Wi[h,:]) + bi[h]   (m = l*B + b)
// 128x128 tile per 256-thread block, BK=16, fp32 vector FMA.
// LDS padded to stride 20 floats (80 B, 16B-aligned) -> <=2-way bank conflicts.
// Thread (tx,ty) computes rows ty+16i, cols tx+16j (i,j in 0..7).
// ---------------------------------------------------------------------------
__global__ __launch_bounds__(256) void xi_gemm(
    const float* __restrict__ x, const float* __restrict__ Wi,
    const float* __restrict__ bi, float* __restrict__ out) {
  __shared__ float As[128][20];
  __shared__ float Bs[128][20];
  const int tid = threadIdx.x;
  const int bm = blockIdx.x;  // 512 row-blocks of M=65536
  const int bn = blockIdx.y;  // 8 col-blocks of N=1024
  const int tx = tid & 15, ty = tid >> 4;
  const float* xA = x + (size_t)bm * 128 * D_;
  const float* wB = Wi + (size_t)bn * 128 * D_;

  float acc[8][8];
#pragma unroll
  for (int i = 0; i < 8; ++i)
#pragma unroll
    for (int j = 0; j < 8; ++j) acc[i][j] = 0.f;

  const int srow = tid >> 2;        // 0..63
  const int scol = (tid & 3) << 2;  // 0,4,8,12

  for (int k0 = 0; k0 < D_; k0 += 16) {
    __syncthreads();
    float4 a0 = *(const float4*)&xA[(size_t)srow * D_ + k0 + scol];
    float4 a1 = *(const float4*)&xA[(size_t)(srow + 64) * D_ + k0 + scol];
    float4 b0 = *(const float4*)&wB[(size_t)srow * D_ + k0 + scol];
    float4 b1 = *(const float4*)&wB[(size_t)(srow + 64) * D_ + k0 + scol];
    *(float4*)&As[srow][scol] = a0;
    *(float4*)&As[srow + 64][scol] = a1;
    *(float4*)&Bs[srow][scol] = b0;
    *(float4*)&Bs[srow + 64][scol] = b1;
    __syncthreads();
#pragma unroll
    for (int kk = 0; kk < 16; kk += 4) {
      float4 a4[8], b4[8];
#pragma unroll
      for (int i = 0; i < 8; ++i) a4[i] = *(const float4*)&As[ty + 16 * i][kk];
#pragma unroll
      for (int j = 0; j < 8; ++j) b4[j] = *(const float4*)&Bs[tx + 16 * j][kk];
#pragma unroll
      for (int i = 0; i < 8; ++i)
#pragma unroll
        for (int j = 0; j < 8; ++j)
          acc[i][j] += a4[i].x * b4[j].x + a4[i].y * b4[j].y +
                       a4[i].z * b4[j].z + a4[i].w * b4[j].w;
    }
  }
#pragma unroll
  for (int j = 0; j < 8; ++j) {
    const int col = bn * 128 + tx + 16 * j;
    const float bias = bi[col];
#pragma unroll
    for (int i = 0; i < 8; ++i) {
      const size_t m = (size_t)bm * 128 + ty + 16 * i;
      out[m * H_ + col] = acc[i][j] + bias;
    }
  }
}

// ---------------------------------------------------------------------------
// Kernel B: sequential scan  h_t = tanh(xi_t + h_{t-1} @ Wh^T + bh)
// 512 blocks x 256 threads, cooperative (co-resident, 2 blocks/CU).
//   g = blockIdx.x & 7  : batch group (16 batches)  -> same XCD round-robin
//   c = blockIdx.x >> 3 : output chunk (16 h-rows of Wh, stationary in LDS)
// Each thread owns one (b, j) output. Per-group barrier: monotonic counter
// in d_ws (agent-scope atomics), release fence before arrive, acquire fence
// after spin (also invalidates L1 -> no stale xi/h lines).
// out[] holds xi on entry; h_t overwrites out[t] in place.
// ---------------------------------------------------------------------------
__global__ __launch_bounds__(256, 2) void rnn_scan(
    const float* __restrict__ h0, const float* __restrict__ Wh,
    const float* __restrict__ bh, float* __restrict__ out,
    unsigned int* __restrict__ bar) {
  __shared__ float Whs[16][1024];  // 64 KB, XOR-swizzled float4 slots
  const int tid = threadIdx.x;
  const int g = blockIdx.x & 7;
  const int c = blockIdx.x >> 3;
  const int b0g = g << 4;
  const int j0 = c << 4;

  // Stage Wh slice: rows j0..j0+15; slot s of row r stored at s ^ (r&7).
#pragma unroll
  for (int it = 0; it < 16; ++it) {
    const int idx = (it << 8) + tid;
    const int r = idx >> 8;
    const int s = idx & 255;
    float4 w = *(const float4*)&Wh[(size_t)(j0 + r) * H_ + (s << 2)];
    *(float4*)&Whs[r][(s ^ (r & 7)) << 2] = w;
  }

  const int lane = tid & 63;
  const int wv = tid >> 6;
  const int jl = (wv << 2) + (lane >> 4);  // 4 distinct j per wave (conflict-free LDS)
  const int bl = lane & 15;                // 16 batches per quarter-wave
  const int j = j0 + jl;
  const int b = b0g + bl;
  const float bias = bh[j];
  const int swz = jl & 7;
  unsigned int* cnt = bar + (g << 6);  // 256 B apart per group
  __syncthreads();

  const float* hrow = h0 + (size_t)b * H_;
  for (int t = 0; t < L_; ++t) {
    float acc = 0.f;
#pragma unroll 8
    for (int s = 0; s < 256; ++s) {
      float4 w = *(const float4*)&Whs[jl][(s ^ swz) << 2];
      float4 h4 = *(const float4*)&hrow[s << 2];
      acc += w.x * h4.x + w.y * h4.y + w.z * h4.z + w.w * h4.w;
    }
    const size_t oidx = ((size_t)t * B_ + b) * H_ + j;
    const float v = tanhf(acc + out[oidx] + bias);
    out[oidx] = v;

    if (t + 1 < L_) {
      __threadfence();   // release our h_t stores agent-wide (cross-XCD safe)
      __syncthreads();
      if (tid == 0) {
        __hip_atomic_fetch_add(cnt, 1u, __ATOMIC_RELEASE, __HIP_MEMORY_SCOPE_AGENT);
        const unsigned target = (unsigned)(t + 1) << 6;  // 64 blocks per group
        while (__hip_atomic_load(cnt, __ATOMIC_RELAXED, __HIP_MEMORY_SCOPE_AGENT) < target)
          __builtin_amdgcn_s_sleep(2);
        __threadfence();  // acquire: invalidate L1/L2 so h_t reads are fresh
      }
      __syncthreads();
    }
    hrow = out + ((size_t)t * B_ + b) * H_;
  }
}

// ---------------------------------------------------------------------------
extern "C" void kernel_launch(void* const* d_in, const int* in_sizes, int n_in,
                              void* d_out, int out_size, void* d_ws, size_t ws_size,
                              hipStream_t stream) {
  const float* x    = (const float*)d_in[0];
  const float* h0   = (const float*)d_in[1];
  const float* Wi_w = (const float*)d_in[2];
  const float* Wi_b = (const float*)d_in[3];
  const float* Wh_w = (const float*)d_in[4];
  const float* Wh_b = (const float*)d_in[5];
  float* out = (float*)d_out;
  unsigned int* bar = (unsigned int*)d_ws;

  // Phase 1: xi -> d_out
  hipLaunchKernelGGL(xi_gemm, dim3(512, 8), dim3(256), 0, stream, x, Wi_w, Wi_b, out);

  // Zero the barrier counters (d_ws is poisoned, not re-poisoned between replays)
  hipMemsetAsync(d_ws, 0, 4096, stream);

  // Phase 2: cooperative scan (co-residency guaranteed for the custom barrier)
  void* args[] = { (void*)&h0, (void*)&Wh_w, (void*)&Wh_b, (void*)&out, (void*)&bar };
  hipLaunchCooperativeKernel((void*)rnn_scan, dim3(512), dim3(256), args, 0, stream);
}

// Round 2
// 19658.080 us; speedup vs baseline: 3.5003x; 3.5003x over previous
//
#include <hip/hip_runtime.h>
#include <cmath>

#define L_ 512
#define B_ 128
#define D_ 1024
#define H_ 1024

// ---------------------------------------------------------------------------
// Kernel A: xi[m][h] = dot(x[m,:], Wi[h,:]) + bi[h]   (m = l*B + b)
// (unchanged from round 1 — known good, ~6.3 ms; will be replaced by
//  split-bf16 MFMA in a later round once the scan is fixed)
// ---------------------------------------------------------------------------
__global__ __launch_bounds__(256) void xi_gemm(
    const float* __restrict__ x, const float* __restrict__ Wi,
    const float* __restrict__ bi, float* __restrict__ out) {
  __shared__ float As[128][20];
  __shared__ float Bs[128][20];
  const int tid = threadIdx.x;
  const int bm = blockIdx.x;
  const int bn = blockIdx.y;
  const int tx = tid & 15, ty = tid >> 4;
  const float* xA = x + (size_t)bm * 128 * D_;
  const float* wB = Wi + (size_t)bn * 128 * D_;

  float acc[8][8];
#pragma unroll
  for (int i = 0; i < 8; ++i)
#pragma unroll
    for (int j = 0; j < 8; ++j) acc[i][j] = 0.f;

  const int srow = tid >> 2;
  const int scol = (tid & 3) << 2;

  for (int k0 = 0; k0 < D_; k0 += 16) {
    __syncthreads();
    float4 a0 = *(const float4*)&xA[(size_t)srow * D_ + k0 + scol];
    float4 a1 = *(const float4*)&xA[(size_t)(srow + 64) * D_ + k0 + scol];
    float4 b0 = *(const float4*)&wB[(size_t)srow * D_ + k0 + scol];
    float4 b1 = *(const float4*)&wB[(size_t)(srow + 64) * D_ + k0 + scol];
    *(float4*)&As[srow][scol] = a0;
    *(float4*)&As[srow + 64][scol] = a1;
    *(float4*)&Bs[srow][scol] = b0;
    *(float4*)&Bs[srow + 64][scol] = b1;
    __syncthreads();
#pragma unroll
    for (int kk = 0; kk < 16; kk += 4) {
      float4 a4[8], b4[8];
#pragma unroll
      for (int i = 0; i < 8; ++i) a4[i] = *(const float4*)&As[ty + 16 * i][kk];
#pragma unroll
      for (int j = 0; j < 8; ++j) b4[j] = *(const float4*)&Bs[tx + 16 * j][kk];
#pragma unroll
      for (int i = 0; i < 8; ++i)
#pragma unroll
        for (int j = 0; j < 8; ++j)
          acc[i][j] += a4[i].x * b4[j].x + a4[i].y * b4[j].y +
                       a4[i].z * b4[j].z + a4[i].w * b4[j].w;
    }
  }
#pragma unroll
  for (int j = 0; j < 8; ++j) {
    const int col = bn * 128 + tx + 16 * j;
    const float bias = bi[col];
#pragma unroll
    for (int i = 0; i < 8; ++i) {
      const size_t m = (size_t)bm * 128 + ty + 16 * i;
      out[m * H_ + col] = acc[i][j] + bias;
    }
  }
}

// ---------------------------------------------------------------------------
// Kernel B v2: h_t = tanh(xi_t + h_{t-1} @ Wh^T + bh)
//
// 512 blocks x 256 threads, cooperative. g = bid & 7 (16 batches, lands on one
// XCD round-robin), c = bid >> 3 (16 Wh rows, stationary in LDS).
//
// Changes vs v1 (which stalled 94% of time):
//  * Barrier: NO atomic RMW. Block release-publishes t+1 to its own flag
//    (relaxed agent atomic store = sc1 write-through, ordered by
//    s_waitcnt vmcnt(0) + __syncthreads). Wave 0 polls all 64 group flags
//    with one 64-lane load + __all. Acquire fence (buffer_inv) after poll.
//    No buffer_wbl2 anywhere: h' elements are written with relaxed agent
//    atomic stores (write-through to coherence point).
//  * Lane map: wave = 16 j x 4 b -> h global loads are 4 lines/instr
//    (16 lanes broadcast same address), LDS w-reads 16 unique addrs.
//  * LDS row stride 1028 floats -> 2-way bank aliasing only (free), and
//    keeps s*16 byte offsets as compile-time immediates.
//  * 4 independent accumulator chains (no serial reduction tree).
// ---------------------------------------------------------------------------
__global__ __launch_bounds__(256, 2) void rnn_scan(
    const float* __restrict__ h0, const float* __restrict__ Wh,
    const float* __restrict__ bh, float* __restrict__ out,
    unsigned int* __restrict__ flags) {
  __shared__ float Whs[16 * 1028];  // 65792 B: row r at r*1028 floats
  const int tid = threadIdx.x;
  const int g = blockIdx.x & 7;
  const int c = blockIdx.x >> 3;
  const int j0 = c << 4;

  // Stage Wh rows j0..j0+15 into LDS (coalesced float4).
#pragma unroll
  for (int it = 0; it < 16; ++it) {
    const int idx = (it << 8) + tid;
    const int r = idx >> 8;
    const int s4 = idx & 255;
    float4 w = *(const float4*)&Wh[(size_t)(j0 + r) * H_ + (s4 << 2)];
    *(float4*)&Whs[r * 1028 + (s4 << 2)] = w;
  }

  const int lane = tid & 63;
  const int wv = tid >> 6;
  const int jl = lane & 15;               // 16 j per wave
  const int bl = (wv << 2) + (lane >> 4); // 4 b per wave, 16 per block
  const int j = j0 + jl;
  const int b = (g << 4) + bl;
  const float bias = bh[j];
  const float* wrow = &Whs[jl * 1028];
  unsigned int* gflags = flags + (g << 6);
  __syncthreads();

  const float* hrow = h0 + (size_t)b * H_;
  for (int t = 0; t < L_; ++t) {
    float a0 = 0.f, a1 = 0.f, a2 = 0.f, a3 = 0.f;
#pragma unroll 8
    for (int s = 0; s < 256; ++s) {
      const float4 w = *(const float4*)&wrow[s << 2];   // ds_read_b128, imm offs
      const float4 h4 = *(const float4*)&hrow[s << 2];  // 4 lines/wave, bcast
      a0 += w.x * h4.x;
      a1 += w.y * h4.y;
      a2 += w.z * h4.z;
      a3 += w.w * h4.w;
    }
    const size_t oidx = ((size_t)t * B_ + b) * H_ + j;
    const float v = tanhf((a0 + a1) + (a2 + a3) + out[oidx] + bias);
    // Write-through to coherence point (sc1) — makes h' agent-visible
    // without any L2 writeback op.
    __hip_atomic_store(&out[oidx], v, __ATOMIC_RELAXED, __HIP_MEMORY_SCOPE_AGENT);

    if (t + 1 < L_) {
      // ---- release: my stores done, then block-wide done, then publish ----
      asm volatile("s_waitcnt vmcnt(0)" ::: "memory");
      __syncthreads();
      if (tid == 0)
        __hip_atomic_store(&gflags[c], (unsigned)(t + 1), __ATOMIC_RELAXED,
                           __HIP_MEMORY_SCOPE_AGENT);
      // ---- acquire: wave 0 polls all 64 flags of the group ----
      if (tid < 64) {
        const unsigned tgt = (unsigned)(t + 1);
        while (true) {
          const unsigned f = __hip_atomic_load(&gflags[tid], __ATOMIC_RELAXED,
                                               __HIP_MEMORY_SCOPE_AGENT);
          if (__all((int)(f >= tgt))) break;
          __builtin_amdgcn_s_sleep(1);
        }
      }
      __syncthreads();
      // Invalidate stale L1/L2 lines (other blocks' h' written through to L3).
      __builtin_amdgcn_fence(__ATOMIC_ACQUIRE, "agent");
    }
    hrow = out + ((size_t)t * B_ + b) * H_;
  }
}

// ---------------------------------------------------------------------------
extern "C" void kernel_launch(void* const* d_in, const int* in_sizes, int n_in,
                              void* d_out, int out_size, void* d_ws, size_t ws_size,
                              hipStream_t stream) {
  const float* x    = (const float*)d_in[0];
  const float* h0   = (const float*)d_in[1];
  const float* Wi_w = (const float*)d_in[2];
  const float* Wi_b = (const float*)d_in[3];
  const float* Wh_w = (const float*)d_in[4];
  const float* Wh_b = (const float*)d_in[5];
  float* out = (float*)d_out;
  unsigned int* flags = (unsigned int*)d_ws;

  // Phase 1: xi -> d_out
  hipLaunchKernelGGL(xi_gemm, dim3(512, 8), dim3(256), 0, stream, x, Wi_w, Wi_b, out);

  // Zero the barrier flags (d_ws is poisoned; not re-poisoned between replays)
  hipMemsetAsync(d_ws, 0, 4096, stream);

  // Phase 2: cooperative scan
  void* args[] = { (void*)&h0, (void*)&Wh_w, (void*)&Wh_b, (void*)&out, (void*)&flags };
  hipLaunchCooperativeKernel((void*)rnn_scan, dim3(512), dim3(256), args, 0, stream);
}

// Round 7
// 17316.776 us; speedup vs baseline: 3.9736x; 1.1352x over previous
//
#include <hip/hip_runtime.h>
#include <cmath>

#define L_ 512
#define B_ 128
#define D_ 1024
#define H_ 1024

typedef __attribute__((ext_vector_type(8))) short bf16x8;
typedef __attribute__((ext_vector_type(4))) float f32x4;

static __device__ __forceinline__ unsigned short f32_bf16_rn(float f) {
  unsigned u = __float_as_uint(f);
  u += 0x7FFFu + ((u >> 16) & 1u);
  return (unsigned short)(u >> 16);
}
static __device__ __forceinline__ float bf16_f32(unsigned short h) {
  return __uint_as_float(((unsigned)h) << 16);
}

// Pack 8 f32 into bf16-hi and bf16-lo fragments (split-bf16: x = hi + lo,
// |lo| <= 2^-9|x|, residual after both ~2^-18 -> fp32-grade 3-MFMA GEMM).
static __device__ __forceinline__ void pack8(const float4& u, const float4& v,
                                             bf16x8& hi, bf16x8& lo) {
  float f[8] = {u.x, u.y, u.z, u.w, v.x, v.y, v.z, v.w};
#pragma unroll
  for (int i = 0; i < 8; ++i) {
    const unsigned short h = f32_bf16_rn(f[i]);
    hi[i] = (short)h;
    lo[i] = (short)f32_bf16_rn(f[i] - bf16_f32(h));
  }
}

// ---------------------------------------------------------------------------
// Kernel A v2: xi = x @ Wi^T + bi via split-bf16 MFMA (3 mfma per fragment:
// hi*hi + hi*lo + lo*hi). 128x128 tile, BK=32, 4 waves in 2x2 quadrants of
// 64x64, each wave 4x4 fragments of 16x16x32.
// gemm_bt pattern: A (x) and B (Wi) are both row-major over k, so both
// fragments load identically: lane l reads row (tile_row + (l&15)), k-block
// (l>>4). C/D: col = lane&15 (Wi row = out col), row = (lane>>4)*4 + reg.
// LDS: 16B slots XOR-swizzled by (row&3) -> 2-way bank alias on ds_read_b128
// (free) instead of 8-way.
// ---------------------------------------------------------------------------
__global__ __launch_bounds__(256) void xi_gemm_mfma(
    const float* __restrict__ x, const float* __restrict__ Wi,
    const float* __restrict__ bi, float* __restrict__ out) {
  __shared__ unsigned short Ahi[128 * 32], Alo[128 * 32];
  __shared__ unsigned short Bhi[128 * 32], Blo[128 * 32];
  const int tid = threadIdx.x;
  const int bm = blockIdx.x, bn = blockIdx.y;
  const int lane = tid & 63, wv = tid >> 6;
  const int wm = wv >> 1, wn = wv & 1;

  const float* Ag = x + (size_t)bm * 128 * D_;
  const float* Bg = Wi + (size_t)bn * 128 * D_;

  f32x4 acc[4][4];
#pragma unroll
  for (int mi = 0; mi < 4; ++mi)
#pragma unroll
    for (int nj = 0; nj < 4; ++nj) acc[mi][nj] = (f32x4){0.f, 0.f, 0.f, 0.f};

  const int r = tid >> 1;   // staged row 0..127
  const int h2 = tid & 1;   // k-half: 16 floats
  const int sw = r & 3;     // slot swizzle
  const int s0 = (h2 * 2) ^ sw, s1 = (h2 * 2 + 1) ^ sw;

  const int fr = lane & 15, kg = lane >> 4;

  for (int k0 = 0; k0 < D_; k0 += 32) {
    __syncthreads();
    {
      const float* pa = &Ag[(size_t)r * D_ + k0 + h2 * 16];
      const float* pb = &Bg[(size_t)r * D_ + k0 + h2 * 16];
      const float4 a0 = *(const float4*)(pa + 0), a1 = *(const float4*)(pa + 4);
      const float4 a2 = *(const float4*)(pa + 8), a3 = *(const float4*)(pa + 12);
      const float4 b0 = *(const float4*)(pb + 0), b1 = *(const float4*)(pb + 4);
      const float4 b2 = *(const float4*)(pb + 8), b3 = *(const float4*)(pb + 12);
      bf16x8 h, l;
      pack8(a0, a1, h, l);
      *(bf16x8*)&Ahi[r * 32 + s0 * 8] = h;
      *(bf16x8*)&Alo[r * 32 + s0 * 8] = l;
      pack8(a2, a3, h, l);
      *(bf16x8*)&Ahi[r * 32 + s1 * 8] = h;
      *(bf16x8*)&Alo[r * 32 + s1 * 8] = l;
      pack8(b0, b1, h, l);
      *(bf16x8*)&Bhi[r * 32 + s0 * 8] = h;
      *(bf16x8*)&Blo[r * 32 + s0 * 8] = l;
      pack8(b2, b3, h, l);
      *(bf16x8*)&Bhi[r * 32 + s1 * 8] = h;
      *(bf16x8*)&Blo[r * 32 + s1 * 8] = l;
    }
    __syncthreads();

    bf16x8 Ah[4], Al[4], Bh[4], Bl[4];
#pragma unroll
    for (int mi = 0; mi < 4; ++mi) {
      const int row = wm * 64 + mi * 16 + fr;
      const int sl = kg ^ (row & 3);
      Ah[mi] = *(const bf16x8*)&Ahi[row * 32 + sl * 8];
      Al[mi] = *(const bf16x8*)&Alo[row * 32 + sl * 8];
    }
#pragma unroll
    for (int nj = 0; nj < 4; ++nj) {
      const int row = wn * 64 + nj * 16 + fr;
      const int sl = kg ^ (row & 3);
      Bh[nj] = *(const bf16x8*)&Bhi[row * 32 + sl * 8];
      Bl[nj] = *(const bf16x8*)&Blo[row * 32 + sl * 8];
    }
#pragma unroll
    for (int mi = 0; mi < 4; ++mi)
#pragma unroll
      for (int nj = 0; nj < 4; ++nj) {
        acc[mi][nj] = __builtin_amdgcn_mfma_f32_16x16x32_bf16(
            Ah[mi], Bh[nj], acc[mi][nj], 0, 0, 0);
        acc[mi][nj] = __builtin_amdgcn_mfma_f32_16x16x32_bf16(
            Ah[mi], Bl[nj], acc[mi][nj], 0, 0, 0);
        acc[mi][nj] = __builtin_amdgcn_mfma_f32_16x16x32_bf16(
            Al[mi], Bh[nj], acc[mi][nj], 0, 0, 0);
      }
  }

  const int fq = lane >> 4;
#pragma unroll
  for (int nj = 0; nj < 4; ++nj) {
    const int col = bn * 128 + wn * 64 + nj * 16 + fr;
    const float bias = bi[col];
#pragma unroll
    for (int mi = 0; mi < 4; ++mi)
#pragma unroll
      for (int reg = 0; reg < 4; ++reg) {
        const size_t row = (size_t)bm * 128 + wm * 64 + mi * 16 + fq * 4 + reg;
        out[row * H_ + col] = acc[mi][nj][reg] + bias;
      }
  }
}

// ---------------------------------------------------------------------------
// Kernel B: VERBATIM the R2 (passed) rnn_scan. Zero changes.
// Post-mortem note: R3-R6 all failed with bit-exact absmax 2.65625 (> 2 =
// impossible for tanh-vs-tanh) => out held raw xi => the cooperative launch
// likely never ran (register-pressure growth from unroll-16/prefetch can
// drop occupancy below 2 blocks/CU and hipLaunchCooperativeKernel rejects
// 512 blocks). Keep this kernel at 88 VGPR; do NOT add live state.
// ---------------------------------------------------------------------------
__global__ __launch_bounds__(256, 2) void rnn_scan(
    const float* __restrict__ h0, const float* __restrict__ Wh,
    const float* __restrict__ bh, float* __restrict__ out,
    unsigned int* __restrict__ flags) {
  __shared__ float Whs[16 * 1028];  // row r at r*1028 floats (2-way bank alias)
  const int tid = threadIdx.x;
  const int g = blockIdx.x & 7;
  const int c = blockIdx.x >> 3;
  const int j0 = c << 4;

#pragma unroll
  for (int it = 0; it < 16; ++it) {
    const int idx = (it << 8) + tid;
    const int r = idx >> 8;
    const int s4 = idx & 255;
    *(float4*)&Whs[r * 1028 + (s4 << 2)] =
        *(const float4*)&Wh[(size_t)(j0 + r) * H_ + (s4 << 2)];
  }

  const int lane = tid & 63;
  const int wv = tid >> 6;
  const int jl = lane & 15;                // 16 j per wave
  const int bl = (wv << 2) + (lane >> 4);  // 4 b per wave, 16 per block
  const int j = j0 + jl;
  const int b = (g << 4) + bl;
  const float bias = bh[j];
  const float* wrow = &Whs[jl * 1028];
  unsigned int* gflags = flags + (g << 6);
  __syncthreads();

  const float* hrow = h0 + (size_t)b * H_;
  for (int t = 0; t < L_; ++t) {
    float a0 = 0.f, a1 = 0.f, a2 = 0.f, a3 = 0.f;
#pragma unroll 8
    for (int s = 0; s < 256; ++s) {
      const float4 w = *(const float4*)&wrow[s << 2];
      const float4 h4 = *(const float4*)&hrow[s << 2];
      a0 += w.x * h4.x;
      a1 += w.y * h4.y;
      a2 += w.z * h4.z;
      a3 += w.w * h4.w;
    }
    const size_t oidx = ((size_t)t * B_ + b) * H_ + j;
    const float v = tanhf((a0 + a1) + (a2 + a3) + out[oidx] + bias);
    __hip_atomic_store(&out[oidx], v, __ATOMIC_RELAXED, __HIP_MEMORY_SCOPE_AGENT);

    if (t + 1 < L_) {
      asm volatile("s_waitcnt vmcnt(0)" ::: "memory");
      __syncthreads();
      if (tid == 0)
        __hip_atomic_store(&gflags[c], (unsigned)(t + 1), __ATOMIC_RELAXED,
                           __HIP_MEMORY_SCOPE_AGENT);
      if (tid < 64) {
        const unsigned tgt = (unsigned)(t + 1);
        while (true) {
          const unsigned f = __hip_atomic_load(&gflags[tid], __ATOMIC_RELAXED,
                                               __HIP_MEMORY_SCOPE_AGENT);
          if (__all((int)(f >= tgt))) break;
          __builtin_amdgcn_s_sleep(1);
        }
      }
      __syncthreads();
      __builtin_amdgcn_fence(__ATOMIC_ACQUIRE, "agent");
    }
    hrow = out + ((size_t)t * B_ + b) * H_;
  }
}

// ---------------------------------------------------------------------------
extern "C" void kernel_launch(void* const* d_in, const int* in_sizes, int n_in,
                              void* d_out, int out_size, void* d_ws, size_t ws_size,
                              hipStream_t stream) {
  const float* x    = (const float*)d_in[0];
  const float* h0   = (const float*)d_in[1];
  const float* Wi_w = (const float*)d_in[2];
  const float* Wi_b = (const float*)d_in[3];
  const float* Wh_w = (const float*)d_in[4];
  const float* Wh_b = (const float*)d_in[5];
  float* out = (float*)d_out;
  unsigned int* flags = (unsigned int*)d_ws;

  // Phase 1: xi -> d_out (split-bf16 MFMA)
  hipLaunchKernelGGL(xi_gemm_mfma, dim3(512, 8), dim3(256), 0, stream,
                     x, Wi_w, Wi_b, out);

  // Zero the barrier flags (graph replays reuse d_ws; flags must start 0)
  hipMemsetAsync(d_ws, 0, 4096, stream);

  // Phase 2: cooperative scan (verbatim R2)
  void* args[] = { (void*)&h0, (void*)&Wh_w, (void*)&Wh_b, (void*)&out, (void*)&flags };
  hipLaunchCooperativeKernel((void*)rnn_scan, dim3(512), dim3(256), args, 0, stream);
}